// Round 1
// baseline (2759.494 us; speedup 1.0000x reference)
//
#include <hip/hip_runtime.h>

// Problem constants
#define NBATCH 8
#define SDIM   1024
#define DDIM   1024
#define NHEAD  16
#define DKDIM  64

// ---------------------------------------------------------------------------
// proj64: Y = X @ W + bias.  X:[8192,1024] W:[1024,1024] row-major.
// 64x64 output tile / block, 256 threads, 4x4 micro-tile, BK=32.
// head_layout=1: write Y in [B,H,S,DK] panels (for attention); else [B,S,D].
// LDS patterns: As row-major [64][36] (pad->2-way), Bs [32][68] (17 f4 odd
// stride -> 2-way on both store & read). A-side reads are 16-lane broadcast.
// ---------------------------------------------------------------------------
__global__ __launch_bounds__(256)
void proj64(const float* __restrict__ X, const float* __restrict__ W,
            const float* __restrict__ bias, float* __restrict__ Y,
            int head_layout)
{
    __shared__ float As[64][36];
    __shared__ float Bs[32][68];
    const int t  = threadIdx.x;
    const int tx = t & 15, ty = t >> 4;
    const int rbase = blockIdx.y << 6;
    const int cbase = blockIdx.x << 6;

    float acc[4][4];
#pragma unroll
    for (int i = 0; i < 4; ++i)
#pragma unroll
        for (int j = 0; j < 4; ++j) acc[i][j] = 0.f;

    for (int kb = 0; kb < DDIM; kb += 32) {
#pragma unroll
        for (int u = 0; u < 2; ++u) {              // X tile 64x32
            int slot = t + (u << 8);
            int r = slot >> 3, sg = slot & 7;
            *(float4*)&As[r][sg * 4] =
                *(const float4*)(X + (size_t)(rbase + r) * DDIM + kb + sg * 4);
        }
#pragma unroll
        for (int u = 0; u < 2; ++u) {              // W tile 32x64
            int slot = t + (u << 8);
            int r = slot >> 4, sg = slot & 15;
            *(float4*)&Bs[r][sg * 4] =
                *(const float4*)(W + (size_t)(kb + r) * DDIM + cbase + sg * 4);
        }
        __syncthreads();
#pragma unroll
        for (int k4 = 0; k4 < 8; ++k4) {
            float4 a[4], bb[4];
#pragma unroll
            for (int i = 0; i < 4; ++i) a[i]  = *(const float4*)&As[ty * 4 + i][k4 * 4];
#pragma unroll
            for (int d = 0; d < 4; ++d) bb[d] = *(const float4*)&Bs[k4 * 4 + d][tx * 4];
#pragma unroll
            for (int d = 0; d < 4; ++d) {
#pragma unroll
                for (int i = 0; i < 4; ++i) {
                    float av = (&a[i].x)[d];
                    acc[i][0] = fmaf(av, bb[d].x, acc[i][0]);
                    acc[i][1] = fmaf(av, bb[d].y, acc[i][1]);
                    acc[i][2] = fmaf(av, bb[d].z, acc[i][2]);
                    acc[i][3] = fmaf(av, bb[d].w, acc[i][3]);
                }
            }
        }
        __syncthreads();
    }

    float4 bv = *(const float4*)(bias + cbase + tx * 4);
    if (head_layout) {
        const int hh = cbase >> 6;                 // tile is 64-aligned: one head
#pragma unroll
        for (int i = 0; i < 4; ++i) {
            int row = rbase + ty * 4 + i;
            int b = row >> 10, s = row & (SDIM - 1);
            float4 o;
            o.x = acc[i][0] + bv.x; o.y = acc[i][1] + bv.y;
            o.z = acc[i][2] + bv.z; o.w = acc[i][3] + bv.w;
            *(float4*)(Y + ((size_t)(b * NHEAD + hh) * SDIM + s) * DKDIM + tx * 4) = o;
        }
    } else {
#pragma unroll
        for (int i = 0; i < 4; ++i) {
            int row = rbase + ty * 4 + i;
            float4 o;
            o.x = acc[i][0] + bv.x; o.y = acc[i][1] + bv.y;
            o.z = acc[i][2] + bv.z; o.w = acc[i][3] + bv.w;
            *(float4*)(Y + (size_t)row * DDIM + cbase + tx * 4) = o;
        }
    }
}

// ---------------------------------------------------------------------------
// attn64: flash-style attention for one (b,h, 64 q-rows) per block.
// scores = QK^T/8, mask|diag -> -1e9, online softmax (m,l per row),
// P = exp(s-m)*group_prob (gp NOT in denominator), acc += P@V, out = acc/l.
// Thread (tx,ty): q-rows ty*4+i; score k-cols STRIDED tx+16j (keeps the
// row-major Ks reads at <=2-way bank aliasing with 68-float stride);
// PV output cols contiguous tx*4+jo. Row softmax reduce = shfl_xor over the
// 16 consecutive lanes sharing ty.
// ---------------------------------------------------------------------------
__global__ __launch_bounds__(256)
void attn64(const float* __restrict__ Qw, const float* __restrict__ Kw,
            const float* __restrict__ Vw, const float* __restrict__ gp,
            const int* __restrict__ mask, float* __restrict__ Xo)
{
    __shared__ float Qs[64][68], Ks[64][68], Vs[64][68], Ps[64][68];
    const int t  = threadIdx.x;
    const int tx = t & 15, ty = t >> 4;
    const int qb = blockIdx.x << 6;
    const int bh = blockIdx.y;                     // b*16 + h
    const int b  = bh >> 4, h = bh & 15;
    const float* Qp = Qw + (size_t)bh * SDIM * DKDIM;
    const float* Kp = Kw + (size_t)bh * SDIM * DKDIM;
    const float* Vp = Vw + (size_t)bh * SDIM * DKDIM;

#pragma unroll
    for (int u = 0; u < 4; ++u) {                  // Q tile 64x64, resident
        int slot = t + (u << 8);
        int r = slot >> 4, sg = slot & 15;
        *(float4*)&Qs[r][sg * 4] =
            *(const float4*)(Qp + (size_t)(qb + r) * DKDIM + sg * 4);
    }

    float m[4], l[4], acc[4][4];
#pragma unroll
    for (int i = 0; i < 4; ++i) {
        m[i] = -3.0e38f; l[i] = 0.f;
#pragma unroll
        for (int j = 0; j < 4; ++j) acc[i][j] = 0.f;
    }

    for (int kt = 0; kt < SDIM / 64; ++kt) {
        const int kbase = kt << 6;
#pragma unroll
        for (int u = 0; u < 4; ++u) {              // K,V tiles 64x64
            int slot = t + (u << 8);
            int r = slot >> 4, sg = slot & 15;
            *(float4*)&Ks[r][sg * 4] =
                *(const float4*)(Kp + (size_t)(kbase + r) * DKDIM + sg * 4);
            *(float4*)&Vs[r][sg * 4] =
                *(const float4*)(Vp + (size_t)(kbase + r) * DKDIM + sg * 4);
        }
        __syncthreads();

        float s[4][4];
#pragma unroll
        for (int i = 0; i < 4; ++i)
#pragma unroll
            for (int j = 0; j < 4; ++j) s[i][j] = 0.f;
#pragma unroll
        for (int d4 = 0; d4 < 16; ++d4) {
            float4 q4[4], k4[4];
#pragma unroll
            for (int i = 0; i < 4; ++i) q4[i] = *(const float4*)&Qs[ty * 4 + i][d4 * 4];
#pragma unroll
            for (int j = 0; j < 4; ++j) k4[j] = *(const float4*)&Ks[tx + 16 * j][d4 * 4];
#pragma unroll
            for (int i = 0; i < 4; ++i)
#pragma unroll
                for (int j = 0; j < 4; ++j) {
                    s[i][j] = fmaf(q4[i].x, k4[j].x, s[i][j]);
                    s[i][j] = fmaf(q4[i].y, k4[j].y, s[i][j]);
                    s[i][j] = fmaf(q4[i].z, k4[j].z, s[i][j]);
                    s[i][j] = fmaf(q4[i].w, k4[j].w, s[i][j]);
                }
        }

#pragma unroll
        for (int i = 0; i < 4; ++i) {
            const int qrow = qb + ty * 4 + i;
            const int*   mrow = mask + ((size_t)b * SDIM + qrow) * SDIM + kbase;
            const float* grow = gp   + ((size_t)b * SDIM + qrow) * SDIM + kbase;
            float sv[4];
#pragma unroll
            for (int j = 0; j < 4; ++j) {
                int kc = tx + 16 * j;
                bool ok = (mrow[kc] != 0) || (qrow == kbase + kc);
                sv[j] = ok ? s[i][j] * 0.125f : -1.0e9f;
            }
            float tm = fmaxf(fmaxf(sv[0], sv[1]), fmaxf(sv[2], sv[3]));
#pragma unroll
            for (int off = 1; off < 16; off <<= 1)
                tm = fmaxf(tm, __shfl_xor(tm, off));
            float mn  = fmaxf(m[i], tm);
            float fac = expf(m[i] - mn);           // first tile: exp(-3e38)=0
            float ts = 0.f, p[4];
#pragma unroll
            for (int j = 0; j < 4; ++j) { p[j] = expf(sv[j] - mn); ts += p[j]; }
#pragma unroll
            for (int off = 1; off < 16; off <<= 1)
                ts += __shfl_xor(ts, off);
            l[i] = l[i] * fac + ts;                // gp NOT in denominator
            m[i] = mn;
#pragma unroll
            for (int j = 0; j < 4; ++j) acc[i][j] *= fac;
#pragma unroll
            for (int j = 0; j < 4; ++j)            // P scaled by group_prob
                Ps[ty * 4 + i][tx + 16 * j] = p[j] * grow[tx + 16 * j];
        }
        __syncthreads();

#pragma unroll
        for (int k4 = 0; k4 < 16; ++k4) {          // acc += P @ V
            float4 p4[4], v4[4];
#pragma unroll
            for (int i = 0; i < 4; ++i) p4[i] = *(const float4*)&Ps[ty * 4 + i][k4 * 4];
#pragma unroll
            for (int d = 0; d < 4; ++d) v4[d] = *(const float4*)&Vs[k4 * 4 + d][tx * 4];
#pragma unroll
            for (int d = 0; d < 4; ++d)
#pragma unroll
                for (int i = 0; i < 4; ++i) {
                    float pv = (&p4[i].x)[d];
                    acc[i][0] = fmaf(pv, v4[d].x, acc[i][0]);
                    acc[i][1] = fmaf(pv, v4[d].y, acc[i][1]);
                    acc[i][2] = fmaf(pv, v4[d].z, acc[i][2]);
                    acc[i][3] = fmaf(pv, v4[d].w, acc[i][3]);
                }
        }
        __syncthreads();
    }

#pragma unroll
    for (int i = 0; i < 4; ++i) {                  // out = acc / l  (l>0: diag)
        const int qrow = qb + ty * 4 + i;
        float inv = 1.f / l[i];
        float4 o;
        o.x = acc[i][0] * inv; o.y = acc[i][1] * inv;
        o.z = acc[i][2] * inv; o.w = acc[i][3] * inv;
        *(float4*)(Xo + ((size_t)b * SDIM + qrow) * DDIM + h * DKDIM + tx * 4) = o;
    }
}

// ---------------------------------------------------------------------------
extern "C" void kernel_launch(void* const* d_in, const int* in_sizes, int n_in,
                              void* d_out, int out_size, void* d_ws, size_t ws_size,
                              hipStream_t stream)
{
    (void)in_sizes; (void)n_in; (void)out_size; (void)ws_size;
    const float* query = (const float*)d_in[0];
    const float* key_  = (const float*)d_in[1];
    const float* value = (const float*)d_in[2];
    const float* gp    = (const float*)d_in[3];
    const int*   mask  = (const int*)d_in[4];
    const float* Wq = (const float*)d_in[5];  const float* bq = (const float*)d_in[6];
    const float* Wk = (const float*)d_in[7];  const float* bk = (const float*)d_in[8];
    const float* Wv = (const float*)d_in[9];  const float* bv = (const float*)d_in[10];
    const float* Wo = (const float*)d_in[11]; const float* bo = (const float*)d_in[12];
    float* out = (float*)d_out;

    const size_t NE = (size_t)NBATCH * SDIM * DDIM;   // 8.39M floats each
    float* Qw = (float*)d_ws;          // [B,H,S,DK]
    float* Kw = Qw + NE;
    float* Vw = Kw + NE;
    float* Xo = Vw + NE;               // [B,S,D]  (ws total: 134 MB)

    dim3 blk(256);
    dim3 gproj(DDIM / 64, (NBATCH * SDIM) / 64);      // 16 x 128
    hipLaunchKernelGGL(proj64, gproj, blk, 0, stream, query, Wq, bq, Qw, 1);
    hipLaunchKernelGGL(proj64, gproj, blk, 0, stream, key_,  Wk, bk, Kw, 1);
    hipLaunchKernelGGL(proj64, gproj, blk, 0, stream, value, Wv, bv, Vw, 1);
    dim3 gattn(SDIM / 64, NBATCH * NHEAD);            // 16 x 128
    hipLaunchKernelGGL(attn64, gattn, blk, 0, stream, Qw, Kw, Vw, gp, mask, Xo);
    hipLaunchKernelGGL(proj64, gproj, blk, 0, stream, Xo, Wo, bo, out, 0);
}

// Round 2
// 1636.544 us; speedup vs baseline: 1.6862x; 1.6862x over previous
//
#include <hip/hip_runtime.h>

// Problem constants
#define NBATCH 8
#define SDIM   1024
#define DDIM   1024
#define NHEAD  16
#define DKDIM  64

// ---------------------------------------------------------------------------
// proj64: Y = X @ W + bias.  X:[8192,1024] W:[1024,1024] row-major.
// 64x64 output tile / block, 256 threads, 4x4 micro-tile, BK=32.
// head_layout=1: write Y in [B,H,S,DK] panels (for attention); else [B,S,D].
// (unchanged from R0: ~220us each, ~78 TF, not the bottleneck)
// ---------------------------------------------------------------------------
__global__ __launch_bounds__(256)
void proj64(const float* __restrict__ X, const float* __restrict__ W,
            const float* __restrict__ bias, float* __restrict__ Y,
            int head_layout)
{
    __shared__ float As[64][36];
    __shared__ float Bs[32][68];
    const int t  = threadIdx.x;
    const int tx = t & 15, ty = t >> 4;
    const int rbase = blockIdx.y << 6;
    const int cbase = blockIdx.x << 6;

    float acc[4][4];
#pragma unroll
    for (int i = 0; i < 4; ++i)
#pragma unroll
        for (int j = 0; j < 4; ++j) acc[i][j] = 0.f;

    for (int kb = 0; kb < DDIM; kb += 32) {
#pragma unroll
        for (int u = 0; u < 2; ++u) {              // X tile 64x32
            int slot = t + (u << 8);
            int r = slot >> 3, sg = slot & 7;
            *(float4*)&As[r][sg * 4] =
                *(const float4*)(X + (size_t)(rbase + r) * DDIM + kb + sg * 4);
        }
#pragma unroll
        for (int u = 0; u < 2; ++u) {              // W tile 32x64
            int slot = t + (u << 8);
            int r = slot >> 4, sg = slot & 15;
            *(float4*)&Bs[r][sg * 4] =
                *(const float4*)(W + (size_t)(kb + r) * DDIM + cbase + sg * 4);
        }
        __syncthreads();
#pragma unroll
        for (int k4 = 0; k4 < 8; ++k4) {
            float4 a[4], bb[4];
#pragma unroll
            for (int i = 0; i < 4; ++i) a[i]  = *(const float4*)&As[ty * 4 + i][k4 * 4];
#pragma unroll
            for (int d = 0; d < 4; ++d) bb[d] = *(const float4*)&Bs[k4 * 4 + d][tx * 4];
#pragma unroll
            for (int d = 0; d < 4; ++d) {
#pragma unroll
                for (int i = 0; i < 4; ++i) {
                    float av = (&a[i].x)[d];
                    acc[i][0] = fmaf(av, bb[d].x, acc[i][0]);
                    acc[i][1] = fmaf(av, bb[d].y, acc[i][1]);
                    acc[i][2] = fmaf(av, bb[d].z, acc[i][2]);
                    acc[i][3] = fmaf(av, bb[d].w, acc[i][3]);
                }
            }
        }
        __syncthreads();
    }

    float4 bv = *(const float4*)(bias + cbase + tx * 4);
    if (head_layout) {
        const int hh = cbase >> 6;                 // tile is 64-aligned: one head
#pragma unroll
        for (int i = 0; i < 4; ++i) {
            int row = rbase + ty * 4 + i;
            int b = row >> 10, s = row & (SDIM - 1);
            float4 o;
            o.x = acc[i][0] + bv.x; o.y = acc[i][1] + bv.y;
            o.z = acc[i][2] + bv.z; o.w = acc[i][3] + bv.w;
            *(float4*)(Y + ((size_t)(b * NHEAD + hh) * SDIM + s) * DKDIM + tx * 4) = o;
        }
    } else {
#pragma unroll
        for (int i = 0; i < 4; ++i) {
            int row = rbase + ty * 4 + i;
            float4 o;
            o.x = acc[i][0] + bv.x; o.y = acc[i][1] + bv.y;
            o.z = acc[i][2] + bv.z; o.w = acc[i][3] + bv.w;
            *(float4*)(Y + (size_t)row * DDIM + cbase + tx * 4) = o;
        }
    }
}

// ---------------------------------------------------------------------------
// attn64 v2: flash-style, one (b,h,64 q-rows) per block.
// R1 changes vs R0 (spill + occupancy fix):
//  - __launch_bounds__(256,3): cap VGPR ~170 -> 3 waves/SIMD
//  - single KVs buffer (K for scores, V for PV): LDS 69.6->52.2 KB -> 3 blk/CU
//  - V staged in registers at tile top (HBM latency hides under score phase),
//    ds_write'd after the post-softmax barrier (T14 async-split pattern)
//  - #pragma unroll 2 on d4/k4 loops: bound live float4 ranges, avoid the
//    hoisting that spilled 2 GB of scratch in R0
// ---------------------------------------------------------------------------
__global__ __launch_bounds__(256, 3)
void attn64(const float* __restrict__ Qw, const float* __restrict__ Kw,
            const float* __restrict__ Vw, const float* __restrict__ gp,
            const int* __restrict__ mask, float* __restrict__ Xo)
{
    __shared__ float Qs[64][68], KVs[64][68], Ps[64][68];
    const int t  = threadIdx.x;
    const int tx = t & 15, ty = t >> 4;
    const int qb = blockIdx.x << 6;
    const int bh = blockIdx.y;                     // b*16 + h
    const int b  = bh >> 4, h = bh & 15;
    const float* Qp = Qw + (size_t)bh * SDIM * DKDIM;
    const float* Kp = Kw + (size_t)bh * SDIM * DKDIM;
    const float* Vp = Vw + (size_t)bh * SDIM * DKDIM;

#pragma unroll
    for (int u = 0; u < 4; ++u) {                  // Q tile 64x64, resident
        int r = ty + 16 * u;
        *(float4*)&Qs[r][tx * 4] =
            *(const float4*)(Qp + (size_t)(qb + r) * DKDIM + tx * 4);
    }

    float m[4], l[4], acc[4][4];
#pragma unroll
    for (int i = 0; i < 4; ++i) {
        m[i] = -3.0e38f; l[i] = 0.f;
#pragma unroll
        for (int j = 0; j < 4; ++j) acc[i][j] = 0.f;
    }

    for (int kt = 0; kt < SDIM / 64; ++kt) {
        const int kbase = kt << 6;

        // Issue K and V global loads together; V parks in registers through
        // the score phase (16 VGPRs), so its latency hides under compute.
        float4 kst[4], vst[4];
#pragma unroll
        for (int u = 0; u < 4; ++u) {
            int r = ty + 16 * u;
            kst[u] = *(const float4*)(Kp + (size_t)(kbase + r) * DKDIM + tx * 4);
            vst[u] = *(const float4*)(Vp + (size_t)(kbase + r) * DKDIM + tx * 4);
        }
#pragma unroll
        for (int u = 0; u < 4; ++u)                // K -> LDS
            *(float4*)&KVs[ty + 16 * u][tx * 4] = kst[u];
        __syncthreads();

        // ---- scores: s[i][j] = Q[row i] . K[col tx+16j] ----
        float s[4][4];
#pragma unroll
        for (int i = 0; i < 4; ++i)
#pragma unroll
            for (int j = 0; j < 4; ++j) s[i][j] = 0.f;
#pragma unroll 2
        for (int d4 = 0; d4 < 16; ++d4) {
            float4 q4[4], k4[4];
#pragma unroll
            for (int i = 0; i < 4; ++i) q4[i] = *(const float4*)&Qs[ty * 4 + i][d4 * 4];
#pragma unroll
            for (int j = 0; j < 4; ++j) k4[j] = *(const float4*)&KVs[tx + 16 * j][d4 * 4];
#pragma unroll
            for (int i = 0; i < 4; ++i)
#pragma unroll
                for (int j = 0; j < 4; ++j) {
                    s[i][j] = fmaf(q4[i].x, k4[j].x, s[i][j]);
                    s[i][j] = fmaf(q4[i].y, k4[j].y, s[i][j]);
                    s[i][j] = fmaf(q4[i].z, k4[j].z, s[i][j]);
                    s[i][j] = fmaf(q4[i].w, k4[j].w, s[i][j]);
                }
        }

        // ---- mask + online softmax + gp modulation ----
#pragma unroll
        for (int i = 0; i < 4; ++i) {
            const int qrow = qb + ty * 4 + i;
            const int*   mrow = mask + ((size_t)b * SDIM + qrow) * SDIM + kbase;
            const float* grow = gp   + ((size_t)b * SDIM + qrow) * SDIM + kbase;
            float sv[4];
#pragma unroll
            for (int j = 0; j < 4; ++j) {
                int kc = tx + 16 * j;
                bool ok = (mrow[kc] != 0) || (qrow == kbase + kc);
                sv[j] = ok ? s[i][j] * 0.125f : -1.0e9f;
            }
            float tm = fmaxf(fmaxf(sv[0], sv[1]), fmaxf(sv[2], sv[3]));
#pragma unroll
            for (int off = 1; off < 16; off <<= 1)
                tm = fmaxf(tm, __shfl_xor(tm, off));
            float mn  = fmaxf(m[i], tm);
            float fac = expf(m[i] - mn);           // first tile: exp(-inf)=0
            float ts = 0.f, p[4];
#pragma unroll
            for (int j = 0; j < 4; ++j) { p[j] = expf(sv[j] - mn); ts += p[j]; }
#pragma unroll
            for (int off = 1; off < 16; off <<= 1)
                ts += __shfl_xor(ts, off);
            l[i] = l[i] * fac + ts;                // gp NOT in denominator
            m[i] = mn;
#pragma unroll
            for (int j = 0; j < 4; ++j) acc[i][j] *= fac;
#pragma unroll
            for (int j = 0; j < 4; ++j)            // P scaled by group_prob
                Ps[ty * 4 + i][tx + 16 * j] = p[j] * grow[tx + 16 * j];
        }
        __syncthreads();                           // K reads done, Ps ready

#pragma unroll
        for (int u = 0; u < 4; ++u)                // V -> LDS (same buffer)
            *(float4*)&KVs[ty + 16 * u][tx * 4] = vst[u];
        __syncthreads();

        // ---- acc += P @ V ----
#pragma unroll 2
        for (int k4 = 0; k4 < 16; ++k4) {
            float4 p4[4], v4[4];
#pragma unroll
            for (int i = 0; i < 4; ++i) p4[i] = *(const float4*)&Ps[ty * 4 + i][k4 * 4];
#pragma unroll
            for (int d = 0; d < 4; ++d) v4[d] = *(const float4*)&KVs[k4 * 4 + d][tx * 4];
#pragma unroll
            for (int d = 0; d < 4; ++d)
#pragma unroll
                for (int i = 0; i < 4; ++i) {
                    float pv = (&p4[i].x)[d];
                    acc[i][0] = fmaf(pv, v4[d].x, acc[i][0]);
                    acc[i][1] = fmaf(pv, v4[d].y, acc[i][1]);
                    acc[i][2] = fmaf(pv, v4[d].z, acc[i][2]);
                    acc[i][3] = fmaf(pv, v4[d].w, acc[i][3]);
                }
        }
        __syncthreads();                           // before next K overwrite
    }

#pragma unroll
    for (int i = 0; i < 4; ++i) {                  // out = acc / l  (l>0: diag)
        const int qrow = qb + ty * 4 + i;
        float inv = 1.f / l[i];
        float4 o;
        o.x = acc[i][0] * inv; o.y = acc[i][1] * inv;
        o.z = acc[i][2] * inv; o.w = acc[i][3] * inv;
        *(float4*)(Xo + ((size_t)b * SDIM + qrow) * DDIM + h * DKDIM + tx * 4) = o;
    }
}

// ---------------------------------------------------------------------------
extern "C" void kernel_launch(void* const* d_in, const int* in_sizes, int n_in,
                              void* d_out, int out_size, void* d_ws, size_t ws_size,
                              hipStream_t stream)
{
    (void)in_sizes; (void)n_in; (void)out_size; (void)ws_size;
    const float* query = (const float*)d_in[0];
    const float* key_  = (const float*)d_in[1];
    const float* value = (const float*)d_in[2];
    const float* gp    = (const float*)d_in[3];
    const int*   mask  = (const int*)d_in[4];
    const float* Wq = (const float*)d_in[5];  const float* bq = (const float*)d_in[6];
    const float* Wk = (const float*)d_in[7];  const float* bk = (const float*)d_in[8];
    const float* Wv = (const float*)d_in[9];  const float* bv = (const float*)d_in[10];
    const float* Wo = (const float*)d_in[11]; const float* bo = (const float*)d_in[12];
    float* out = (float*)d_out;

    const size_t NE = (size_t)NBATCH * SDIM * DDIM;   // 8.39M floats each
    float* Qw = (float*)d_ws;          // [B,H,S,DK]
    float* Kw = Qw + NE;
    float* Vw = Kw + NE;
    float* Xo = Vw + NE;               // [B,S,D]  (ws total: 134 MB)

    dim3 blk(256);
    dim3 gproj(DDIM / 64, (NBATCH * SDIM) / 64);      // 16 x 128
    hipLaunchKernelGGL(proj64, gproj, blk, 0, stream, query, Wq, bq, Qw, 1);
    hipLaunchKernelGGL(proj64, gproj, blk, 0, stream, key_,  Wk, bk, Kw, 1);
    hipLaunchKernelGGL(proj64, gproj, blk, 0, stream, value, Wv, bv, Vw, 1);
    dim3 gattn(SDIM / 64, NBATCH * NHEAD);            // 16 x 128
    hipLaunchKernelGGL(attn64, gattn, blk, 0, stream, Qw, Kw, Vw, gp, mask, Xo);
    hipLaunchKernelGGL(proj64, gproj, blk, 0, stream, Xo, Wo, bo, out, 0);
}

// Round 3
// 1114.052 us; speedup vs baseline: 2.4770x; 1.4690x over previous
//
#include <hip/hip_runtime.h>

// Problem constants
#define NBATCH 8
#define SDIM   1024
#define DDIM   1024
#define NHEAD  16
#define DKDIM  64

typedef __attribute__((ext_vector_type(8))) short  short8;   // 8 bf16 (4 VGPR)
typedef __attribute__((ext_vector_type(4))) float  f32x4;    // MFMA acc

// round-to-nearest-even bf16 bits of x
__device__ __forceinline__ unsigned bf16rne(float x) {
    unsigned u = __float_as_uint(x);
    return (u + 0x7fffu + ((u >> 16) & 1u)) >> 16;
}

// ---------------------------------------------------------------------------
// proj_mfma: Y = X@W + bias via split-bf16 3-pass MFMA (hh + hl + lh).
// X:[8192,1024] W:[1024,1024] row-major fp32. 128x128 tile/block, 256 thr =
// 4 waves (2x2, 64x64 each), BK=32, mfma_f32_16x16x32_bf16, 48 MFMA/wave/Kstep.
// fp32->hi/lo bf16 split happens in reg-staging (VGPR round-trip required).
// LDS rows stride 40 ushort (80B): frag reads 16B-aligned, ~uniform banks.
// B staged TRANSPOSED (Bt[n][k]) so b-frags read contiguous along k.
// XCD swizzle: flat%8 = xcd owns 64 consecutive logical tiles (8 full A-rows
// reuse in its L2; B (4MB) read once per XCD).
// head_layout=1: scatter to [B,H,S,DK]; else [B,S,D].
// ---------------------------------------------------------------------------
__global__ __launch_bounds__(256, 2)
void proj_mfma(const float* __restrict__ X, const float* __restrict__ W,
               const float* __restrict__ bias, float* __restrict__ Y,
               int head_layout)
{
    __shared__ unsigned short Ah[128 * 40], Al[128 * 40];
    __shared__ unsigned short Bh[128 * 40], Bl[128 * 40];

    const int t    = threadIdx.x;
    const int lane = t & 63, wid = t >> 6;
    const int wr   = wid >> 1, wc = wid & 1;       // wave 2x2 -> 64x64 each
    const int lr   = lane & 15, lg = lane >> 4;

    // XCD-chunked swizzle (512 blocks = 8 xcd * 64 tiles, bijective)
    const int flat    = blockIdx.x;
    const int logical = (flat & 7) * 64 + (flat >> 3);
    const int by = logical >> 3, bx = logical & 7;
    const int rbase = by << 7, cbase = bx << 7;

    f32x4 acc[4][4];
#pragma unroll
    for (int i = 0; i < 4; ++i)
#pragma unroll
        for (int j = 0; j < 4; ++j) acc[i][j] = (f32x4){0.f, 0.f, 0.f, 0.f};

    float4 aR[4];
    float  bR[4][4];

    // A tile: slot=t+256u: arow=slot>>3 (0..127), ac4=slot&7 (float4 col grp)
    // B tile: slot=t+256u: bn=slot&127, kq=slot>>7 -> k0=4*kq (4 scalar rows)
#define LOAD_TILE(KB)                                                          \
    {                                                                          \
        _Pragma("unroll")                                                      \
        for (int u = 0; u < 4; ++u) {                                          \
            int slot = t + (u << 8);                                           \
            int arow = slot >> 3, ac4 = slot & 7;                              \
            aR[u] = *(const float4*)(X + (size_t)(rbase + arow) * DDIM         \
                                       + (KB) + ac4 * 4);                      \
        }                                                                      \
        _Pragma("unroll")                                                      \
        for (int u = 0; u < 4; ++u) {                                          \
            int slot = t + (u << 8);                                           \
            int bn = slot & 127, k0 = (slot >> 7) << 2;                        \
            _Pragma("unroll")                                                  \
            for (int e = 0; e < 4; ++e)                                        \
                bR[u][e] = W[(size_t)((KB) + k0 + e) * DDIM + cbase + bn];     \
        }                                                                      \
    }

    LOAD_TILE(0)

    for (int kt = 0; kt < DDIM / 32; ++kt) {
        // ---- convert & store staged tile to LDS ----
#pragma unroll
        for (int u = 0; u < 4; ++u) {
            int slot = t + (u << 8);
            int arow = slot >> 3, ac4 = slot & 7;
            float4 v = aR[u];
            unsigned h0 = bf16rne(v.x), h1 = bf16rne(v.y),
                     h2 = bf16rne(v.z), h3 = bf16rne(v.w);
            float r0 = v.x - __uint_as_float(h0 << 16);
            float r1 = v.y - __uint_as_float(h1 << 16);
            float r2 = v.z - __uint_as_float(h2 << 16);
            float r3 = v.w - __uint_as_float(h3 << 16);
            uint2 hv, lv;
            hv.x = h0 | (h1 << 16);           hv.y = h2 | (h3 << 16);
            lv.x = bf16rne(r0) | (bf16rne(r1) << 16);
            lv.y = bf16rne(r2) | (bf16rne(r3) << 16);
            *(uint2*)&Ah[arow * 40 + ac4 * 4] = hv;
            *(uint2*)&Al[arow * 40 + ac4 * 4] = lv;
        }
#pragma unroll
        for (int u = 0; u < 4; ++u) {
            int slot = t + (u << 8);
            int bn = slot & 127, k0 = (slot >> 7) << 2;
            unsigned h[4], l[4];
#pragma unroll
            for (int e = 0; e < 4; ++e) {
                h[e] = bf16rne(bR[u][e]);
                l[e] = bf16rne(bR[u][e] - __uint_as_float(h[e] << 16));
            }
            uint2 hv, lv;
            hv.x = h[0] | (h[1] << 16);  hv.y = h[2] | (h[3] << 16);
            lv.x = l[0] | (l[1] << 16);  lv.y = l[2] | (l[3] << 16);
            *(uint2*)&Bh[bn * 40 + k0] = hv;   // Bt[n][k] transposed store
            *(uint2*)&Bl[bn * 40 + k0] = lv;
        }
        __syncthreads();

        if (kt < DDIM / 32 - 1) LOAD_TILE((kt + 1) << 5)   // overlap w/ MFMA

        // ---- fragment reads + 3-pass MFMA ----
        short8 ah[4], al4[4], bh4[4], bl4[4];
#pragma unroll
        for (int i = 0; i < 4; ++i) {
            int row = wr * 64 + i * 16 + lr;
            ah[i]  = *(const short8*)&Ah[row * 40 + lg * 8];
            al4[i] = *(const short8*)&Al[row * 40 + lg * 8];
        }
#pragma unroll
        for (int j = 0; j < 4; ++j) {
            int col = wc * 64 + j * 16 + lr;
            bh4[j] = *(const short8*)&Bh[col * 40 + lg * 8];
            bl4[j] = *(const short8*)&Bl[col * 40 + lg * 8];
        }
#pragma unroll
        for (int i = 0; i < 4; ++i)
#pragma unroll
            for (int j = 0; j < 4; ++j) {
                acc[i][j] = __builtin_amdgcn_mfma_f32_16x16x32_bf16(
                    ah[i], bh4[j], acc[i][j], 0, 0, 0);
                acc[i][j] = __builtin_amdgcn_mfma_f32_16x16x32_bf16(
                    ah[i], bl4[j], acc[i][j], 0, 0, 0);
                acc[i][j] = __builtin_amdgcn_mfma_f32_16x16x32_bf16(
                    al4[i], bh4[j], acc[i][j], 0, 0, 0);
            }
        __syncthreads();
    }
#undef LOAD_TILE

    // ---- epilogue: bias + store (C/D: col=lane&15, row=(lane>>4)*4+reg) ----
#pragma unroll
    for (int j = 0; j < 4; ++j) {
        int gcol = cbase + wc * 64 + j * 16 + lr;
        float bv = bias[gcol];
        int h = gcol >> 6, dk = gcol & 63;
#pragma unroll
        for (int i = 0; i < 4; ++i) {
#pragma unroll
            for (int rr = 0; rr < 4; ++rr) {
                int grow = rbase + wr * 64 + i * 16 + lg * 4 + rr;
                float val = acc[i][j][rr] + bv;
                if (head_layout) {
                    int b = grow >> 10, s = grow & (SDIM - 1);
                    Y[(((size_t)(b * NHEAD + h) * SDIM + s) << 6) + dk] = val;
                } else {
                    Y[(size_t)grow * DDIM + gcol] = val;
                }
            }
        }
    }
}

// ---------------------------------------------------------------------------
// attn64: unchanged from R2 (665us, fp32 flash-style, 3 blk/CU).
// ---------------------------------------------------------------------------
__global__ __launch_bounds__(256, 3)
void attn64(const float* __restrict__ Qw, const float* __restrict__ Kw,
            const float* __restrict__ Vw, const float* __restrict__ gp,
            const int* __restrict__ mask, float* __restrict__ Xo)
{
    __shared__ float Qs[64][68], KVs[64][68], Ps[64][68];
    const int t  = threadIdx.x;
    const int tx = t & 15, ty = t >> 4;
    const int qb = blockIdx.x << 6;
    const int bh = blockIdx.y;                     // b*16 + h
    const int b  = bh >> 4, h = bh & 15;
    const float* Qp = Qw + (size_t)bh * SDIM * DKDIM;
    const float* Kp = Kw + (size_t)bh * SDIM * DKDIM;
    const float* Vp = Vw + (size_t)bh * SDIM * DKDIM;

#pragma unroll
    for (int u = 0; u < 4; ++u) {                  // Q tile 64x64, resident
        int r = ty + 16 * u;
        *(float4*)&Qs[r][tx * 4] =
            *(const float4*)(Qp + (size_t)(qb + r) * DKDIM + tx * 4);
    }

    float m[4], l[4], acc[4][4];
#pragma unroll
    for (int i = 0; i < 4; ++i) {
        m[i] = -3.0e38f; l[i] = 0.f;
#pragma unroll
        for (int j = 0; j < 4; ++j) acc[i][j] = 0.f;
    }

    for (int kt = 0; kt < SDIM / 64; ++kt) {
        const int kbase = kt << 6;

        float4 kst[4], vst[4];
#pragma unroll
        for (int u = 0; u < 4; ++u) {
            int r = ty + 16 * u;
            kst[u] = *(const float4*)(Kp + (size_t)(kbase + r) * DKDIM + tx * 4);
            vst[u] = *(const float4*)(Vp + (size_t)(kbase + r) * DKDIM + tx * 4);
        }
#pragma unroll
        for (int u = 0; u < 4; ++u)                // K -> LDS
            *(float4*)&KVs[ty + 16 * u][tx * 4] = kst[u];
        __syncthreads();

        float s[4][4];
#pragma unroll
        for (int i = 0; i < 4; ++i)
#pragma unroll
            for (int j = 0; j < 4; ++j) s[i][j] = 0.f;
#pragma unroll 2
        for (int d4 = 0; d4 < 16; ++d4) {
            float4 q4[4], k4[4];
#pragma unroll
            for (int i = 0; i < 4; ++i) q4[i] = *(const float4*)&Qs[ty * 4 + i][d4 * 4];
#pragma unroll
            for (int j = 0; j < 4; ++j) k4[j] = *(const float4*)&KVs[tx + 16 * j][d4 * 4];
#pragma unroll
            for (int i = 0; i < 4; ++i)
#pragma unroll
                for (int j = 0; j < 4; ++j) {
                    s[i][j] = fmaf(q4[i].x, k4[j].x, s[i][j]);
                    s[i][j] = fmaf(q4[i].y, k4[j].y, s[i][j]);
                    s[i][j] = fmaf(q4[i].z, k4[j].z, s[i][j]);
                    s[i][j] = fmaf(q4[i].w, k4[j].w, s[i][j]);
                }
        }

#pragma unroll
        for (int i = 0; i < 4; ++i) {
            const int qrow = qb + ty * 4 + i;
            const int*   mrow = mask + ((size_t)b * SDIM + qrow) * SDIM + kbase;
            const float* grow = gp   + ((size_t)b * SDIM + qrow) * SDIM + kbase;
            float sv[4];
#pragma unroll
            for (int j = 0; j < 4; ++j) {
                int kc = tx + 16 * j;
                bool ok = (mrow[kc] != 0) || (qrow == kbase + kc);
                sv[j] = ok ? s[i][j] * 0.125f : -1.0e9f;
            }
            float tm = fmaxf(fmaxf(sv[0], sv[1]), fmaxf(sv[2], sv[3]));
#pragma unroll
            for (int off = 1; off < 16; off <<= 1)
                tm = fmaxf(tm, __shfl_xor(tm, off));
            float mn  = fmaxf(m[i], tm);
            float fac = expf(m[i] - mn);
            float ts = 0.f, p[4];
#pragma unroll
            for (int j = 0; j < 4; ++j) { p[j] = expf(sv[j] - mn); ts += p[j]; }
#pragma unroll
            for (int off = 1; off < 16; off <<= 1)
                ts += __shfl_xor(ts, off);
            l[i] = l[i] * fac + ts;                // gp NOT in denominator
            m[i] = mn;
#pragma unroll
            for (int j = 0; j < 4; ++j) acc[i][j] *= fac;
#pragma unroll
            for (int j = 0; j < 4; ++j)
                Ps[ty * 4 + i][tx + 16 * j] = p[j] * grow[tx + 16 * j];
        }
        __syncthreads();

#pragma unroll
        for (int u = 0; u < 4; ++u)                // V -> LDS (same buffer)
            *(float4*)&KVs[ty + 16 * u][tx * 4] = vst[u];
        __syncthreads();

#pragma unroll 2
        for (int k4 = 0; k4 < 16; ++k4) {
            float4 p4[4], v4[4];
#pragma unroll
            for (int i = 0; i < 4; ++i) p4[i] = *(const float4*)&Ps[ty * 4 + i][k4 * 4];
#pragma unroll
            for (int d = 0; d < 4; ++d) v4[d] = *(const float4*)&KVs[k4 * 4 + d][tx * 4];
#pragma unroll
            for (int d = 0; d < 4; ++d)
#pragma unroll
                for (int i = 0; i < 4; ++i) {
                    float pv = (&p4[i].x)[d];
                    acc[i][0] = fmaf(pv, v4[d].x, acc[i][0]);
                    acc[i][1] = fmaf(pv, v4[d].y, acc[i][1]);
                    acc[i][2] = fmaf(pv, v4[d].z, acc[i][2]);
                    acc[i][3] = fmaf(pv, v4[d].w, acc[i][3]);
                }
        }
        __syncthreads();
    }

#pragma unroll
    for (int i = 0; i < 4; ++i) {
        const int qrow = qb + ty * 4 + i;
        float inv = 1.f / l[i];
        float4 o;
        o.x = acc[i][0] * inv; o.y = acc[i][1] * inv;
        o.z = acc[i][2] * inv; o.w = acc[i][3] * inv;
        *(float4*)(Xo + ((size_t)b * SDIM + qrow) * DDIM + h * DKDIM + tx * 4) = o;
    }
}

// ---------------------------------------------------------------------------
extern "C" void kernel_launch(void* const* d_in, const int* in_sizes, int n_in,
                              void* d_out, int out_size, void* d_ws, size_t ws_size,
                              hipStream_t stream)
{
    (void)in_sizes; (void)n_in; (void)out_size; (void)ws_size;
    const float* query = (const float*)d_in[0];
    const float* key_  = (const float*)d_in[1];
    const float* value = (const float*)d_in[2];
    const float* gp    = (const float*)d_in[3];
    const int*   mask  = (const int*)d_in[4];
    const float* Wq = (const float*)d_in[5];  const float* bq = (const float*)d_in[6];
    const float* Wk = (const float*)d_in[7];  const float* bk = (const float*)d_in[8];
    const float* Wv = (const float*)d_in[9];  const float* bv = (const float*)d_in[10];
    const float* Wo = (const float*)d_in[11]; const float* bo = (const float*)d_in[12];
    float* out = (float*)d_out;

    const size_t NE = (size_t)NBATCH * SDIM * DDIM;   // 8.39M floats each
    float* Qw = (float*)d_ws;          // [B,H,S,DK]
    float* Kw = Qw + NE;
    float* Vw = Kw + NE;
    float* Xo = Vw + NE;               // [B,S,D]  (ws total: 134 MB)

    dim3 blk(256);
    dim3 gproj(512);                                  // 128x128 tiles, swizzled
    hipLaunchKernelGGL(proj_mfma, gproj, blk, 0, stream, query, Wq, bq, Qw, 1);
    hipLaunchKernelGGL(proj_mfma, gproj, blk, 0, stream, key_,  Wk, bk, Kw, 1);
    hipLaunchKernelGGL(proj_mfma, gproj, blk, 0, stream, value, Wv, bv, Vw, 1);
    dim3 gattn(SDIM / 64, NBATCH * NHEAD);            // 16 x 128
    hipLaunchKernelGGL(attn64, gattn, blk, 0, stream, Qw, Kw, Vw, gp, mask, Xo);
    hipLaunchKernelGGL(proj_mfma, gproj, blk, 0, stream, Xo, Wo, bo, out, 0);
}

// Round 4
// 856.844 us; speedup vs baseline: 3.2205x; 1.3002x over previous
//
#include <hip/hip_runtime.h>

// Problem constants
#define NBATCH 8
#define SDIM   1024
#define DDIM   1024
#define NHEAD  16
#define DKDIM  64

typedef __attribute__((ext_vector_type(8))) short  short8;   // 8 bf16 (4 VGPR)
typedef __attribute__((ext_vector_type(4))) float  f32x4;    // MFMA acc

// round-to-nearest-even bf16 bits of x
__device__ __forceinline__ unsigned bf16rne(float x) {
    unsigned u = __float_as_uint(x);
    return (u + 0x7fffu + ((u >> 16) & 1u)) >> 16;
}

// ---------------------------------------------------------------------------
// proj_mfma: unchanged from R3 (~108us each, split-bf16 3-pass MFMA).
// ---------------------------------------------------------------------------
__global__ __launch_bounds__(256, 2)
void proj_mfma(const float* __restrict__ X, const float* __restrict__ W,
               const float* __restrict__ bias, float* __restrict__ Y,
               int head_layout)
{
    __shared__ unsigned short Ah[128 * 40], Al[128 * 40];
    __shared__ unsigned short Bh[128 * 40], Bl[128 * 40];

    const int t    = threadIdx.x;
    const int lane = t & 63, wid = t >> 6;
    const int wr   = wid >> 1, wc = wid & 1;       // wave 2x2 -> 64x64 each
    const int lr   = lane & 15, lg = lane >> 4;

    const int flat    = blockIdx.x;
    const int logical = (flat & 7) * 64 + (flat >> 3);
    const int by = logical >> 3, bx = logical & 7;
    const int rbase = by << 7, cbase = bx << 7;

    f32x4 acc[4][4];
#pragma unroll
    for (int i = 0; i < 4; ++i)
#pragma unroll
        for (int j = 0; j < 4; ++j) acc[i][j] = (f32x4){0.f, 0.f, 0.f, 0.f};

    float4 aR[4];
    float  bR[4][4];

#define LOAD_TILE(KB)                                                          \
    {                                                                          \
        _Pragma("unroll")                                                      \
        for (int u = 0; u < 4; ++u) {                                          \
            int slot = t + (u << 8);                                           \
            int arow = slot >> 3, ac4 = slot & 7;                              \
            aR[u] = *(const float4*)(X + (size_t)(rbase + arow) * DDIM         \
                                       + (KB) + ac4 * 4);                      \
        }                                                                      \
        _Pragma("unroll")                                                      \
        for (int u = 0; u < 4; ++u) {                                          \
            int slot = t + (u << 8);                                           \
            int bn = slot & 127, k0 = (slot >> 7) << 2;                        \
            _Pragma("unroll")                                                  \
            for (int e = 0; e < 4; ++e)                                        \
                bR[u][e] = W[(size_t)((KB) + k0 + e) * DDIM + cbase + bn];     \
        }                                                                      \
    }

    LOAD_TILE(0)

    for (int kt = 0; kt < DDIM / 32; ++kt) {
#pragma unroll
        for (int u = 0; u < 4; ++u) {
            int slot = t + (u << 8);
            int arow = slot >> 3, ac4 = slot & 7;
            float4 v = aR[u];
            unsigned h0 = bf16rne(v.x), h1 = bf16rne(v.y),
                     h2 = bf16rne(v.z), h3 = bf16rne(v.w);
            float r0 = v.x - __uint_as_float(h0 << 16);
            float r1 = v.y - __uint_as_float(h1 << 16);
            float r2 = v.z - __uint_as_float(h2 << 16);
            float r3 = v.w - __uint_as_float(h3 << 16);
            uint2 hv, lv;
            hv.x = h0 | (h1 << 16);           hv.y = h2 | (h3 << 16);
            lv.x = bf16rne(r0) | (bf16rne(r1) << 16);
            lv.y = bf16rne(r2) | (bf16rne(r3) << 16);
            *(uint2*)&Ah[arow * 40 + ac4 * 4] = hv;
            *(uint2*)&Al[arow * 40 + ac4 * 4] = lv;
        }
#pragma unroll
        for (int u = 0; u < 4; ++u) {
            int slot = t + (u << 8);
            int bn = slot & 127, k0 = (slot >> 7) << 2;
            unsigned h[4], l[4];
#pragma unroll
            for (int e = 0; e < 4; ++e) {
                h[e] = bf16rne(bR[u][e]);
                l[e] = bf16rne(bR[u][e] - __uint_as_float(h[e] << 16));
            }
            uint2 hv, lv;
            hv.x = h[0] | (h[1] << 16);  hv.y = h[2] | (h[3] << 16);
            lv.x = l[0] | (l[1] << 16);  lv.y = l[2] | (l[3] << 16);
            *(uint2*)&Bh[bn * 40 + k0] = hv;
            *(uint2*)&Bl[bn * 40 + k0] = lv;
        }
        __syncthreads();

        if (kt < DDIM / 32 - 1) LOAD_TILE((kt + 1) << 5)

        short8 ah[4], al4[4], bh4[4], bl4[4];
#pragma unroll
        for (int i = 0; i < 4; ++i) {
            int row = wr * 64 + i * 16 + lr;
            ah[i]  = *(const short8*)&Ah[row * 40 + lg * 8];
            al4[i] = *(const short8*)&Al[row * 40 + lg * 8];
        }
#pragma unroll
        for (int j = 0; j < 4; ++j) {
            int col = wc * 64 + j * 16 + lr;
            bh4[j] = *(const short8*)&Bh[col * 40 + lg * 8];
            bl4[j] = *(const short8*)&Bl[col * 40 + lg * 8];
        }
#pragma unroll
        for (int i = 0; i < 4; ++i)
#pragma unroll
            for (int j = 0; j < 4; ++j) {
                acc[i][j] = __builtin_amdgcn_mfma_f32_16x16x32_bf16(
                    ah[i], bh4[j], acc[i][j], 0, 0, 0);
                acc[i][j] = __builtin_amdgcn_mfma_f32_16x16x32_bf16(
                    ah[i], bl4[j], acc[i][j], 0, 0, 0);
                acc[i][j] = __builtin_amdgcn_mfma_f32_16x16x32_bf16(
                    al4[i], bh4[j], acc[i][j], 0, 0, 0);
            }
        __syncthreads();
    }
#undef LOAD_TILE

#pragma unroll
    for (int j = 0; j < 4; ++j) {
        int gcol = cbase + wc * 64 + j * 16 + lr;
        float bv = bias[gcol];
        int h = gcol >> 6, dk = gcol & 63;
#pragma unroll
        for (int i = 0; i < 4; ++i) {
#pragma unroll
            for (int rr = 0; rr < 4; ++rr) {
                int grow = rbase + wr * 64 + i * 16 + lg * 4 + rr;
                float val = acc[i][j][rr] + bv;
                if (head_layout) {
                    int b = grow >> 10, s = grow & (SDIM - 1);
                    Y[(((size_t)(b * NHEAD + h) * SDIM + s) << 6) + dk] = val;
                } else {
                    Y[(size_t)grow * DDIM + gcol] = val;
                }
            }
        }
    }
}

// ---------------------------------------------------------------------------
// attn_mfma: flash attention, MFMA everywhere.
// Block = 128 q-rows x (b,h); 4 waves x 32 rows. KVBLK=64.
// QK^T: split-bf16 3-pass (score accuracy ~1e-4). PV: single bf16 (P,V).
// Q-frags resident in registers; K hi/lo in LDS; V: fp32 LDS scratch ->
// transposed bf16 Vt[d][k]; P round-trips via U.pm (aliases V scratch,
// disjoint in time: vs read pre-b2, pm written post-b2).
// All LDS patterns <=2-way bank aliasing (free per m136).
// Barriers/tile: b1(staged) -> QK+transpose+softmax -> b2 -> Pm+PV -> b3.
// Next tile's K/V global loads issued at b2 (latency hides under PV).
// ---------------------------------------------------------------------------
union AttnSh { float vs[64 * 68]; unsigned short pm[128 * 72]; };

__global__ __launch_bounds__(256, 2)
void attn_mfma(const float* __restrict__ Qw, const float* __restrict__ Kw,
               const float* __restrict__ Vw, const float* __restrict__ gp,
               const int* __restrict__ mask, float* __restrict__ Xo)
{
    __shared__ unsigned short Kh[64 * 72], Kl[64 * 72];
    __shared__ unsigned short Vt[64 * 72];           // [d][k] bf16
    __shared__ AttnSh U;

    const int t    = threadIdx.x;
    const int lane = t & 63, w = t >> 6;
    const int lr   = lane & 15, lg = lane >> 4;

    // XCD-chunked swizzle: 1024 blocks; 8 q-blocks of one (b,h) share an XCD
    const int flat    = blockIdx.x;
    const int logical = (flat & 7) * 128 + (flat >> 3);
    const int bh = logical >> 3, qbi = logical & 7;
    const int b  = bh >> 4, h = bh & 15;
    const int qb0 = qbi << 7;

    const float* Qp = Qw + (size_t)bh * SDIM * DKDIM;
    const float* Kp = Kw + (size_t)bh * SDIM * DKDIM;
    const float* Vp = Vw + (size_t)bh * SDIM * DKDIM;

    // ---- Q fragments in registers (one-time) ----
    short8 qh[2][2], ql[2][2];
#pragma unroll
    for (int i = 0; i < 2; ++i)
#pragma unroll
        for (int kk = 0; kk < 2; ++kk) {
            const float* src = Qp + (size_t)(qb0 + w * 32 + i * 16 + lr) * DKDIM
                                  + kk * 32 + lg * 8;
            float4 a = *(const float4*)src;
            float4 c = *(const float4*)(src + 4);
            float f[8] = {a.x, a.y, a.z, a.w, c.x, c.y, c.z, c.w};
            short8 hh, ll;
#pragma unroll
            for (int e = 0; e < 8; ++e) {
                unsigned hb = bf16rne(f[e]);
                hh[e] = (short)hb;
                ll[e] = (short)bf16rne(f[e] - __uint_as_float(hb << 16));
            }
            qh[i][kk] = hh; ql[i][kk] = ll;
        }

    float mreg[8], lreg[8];
    f32x4 pv[2][4];
#pragma unroll
    for (int r = 0; r < 8; ++r) { mreg[r] = -3.0e38f; lreg[r] = 0.f; }
#pragma unroll
    for (int i = 0; i < 2; ++i)
#pragma unroll
        for (int j = 0; j < 4; ++j) pv[i][j] = (f32x4){0.f, 0.f, 0.f, 0.f};

    float4 kst[4], vst[4];

#define LOADKV(KB)                                                             \
    {                                                                          \
        _Pragma("unroll")                                                      \
        for (int u = 0; u < 4; ++u) {                                          \
            int slot = t + (u << 8);                                           \
            int krow = slot >> 4, f4i = slot & 15;                             \
            kst[u] = *(const float4*)(Kp + (size_t)((KB) + krow) * DKDIM + f4i * 4); \
            vst[u] = *(const float4*)(Vp + (size_t)((KB) + krow) * DKDIM + f4i * 4); \
        }                                                                      \
    }

#define STOREKV()                                                              \
    {                                                                          \
        _Pragma("unroll")                                                      \
        for (int u = 0; u < 4; ++u) {                                          \
            int slot = t + (u << 8);                                           \
            int krow = slot >> 4, f4i = slot & 15;                             \
            float f[4] = {kst[u].x, kst[u].y, kst[u].z, kst[u].w};             \
            unsigned hb[4], lb[4];                                             \
            _Pragma("unroll")                                                  \
            for (int e = 0; e < 4; ++e) {                                      \
                hb[e] = bf16rne(f[e]);                                         \
                lb[e] = bf16rne(f[e] - __uint_as_float(hb[e] << 16));          \
            }                                                                  \
            uint2 hv, lv;                                                      \
            hv.x = hb[0] | (hb[1] << 16); hv.y = hb[2] | (hb[3] << 16);        \
            lv.x = lb[0] | (lb[1] << 16); lv.y = lb[2] | (lb[3] << 16);        \
            *(uint2*)&Kh[krow * 72 + f4i * 4] = hv;                            \
            *(uint2*)&Kl[krow * 72 + f4i * 4] = lv;                            \
            *(float4*)&U.vs[krow * 68 + f4i * 4] = vst[u];                     \
        }                                                                      \
    }

    LOADKV(0)
    STOREKV()
    __syncthreads();                               // tile 0 staged

    for (int kt = 0; kt < SDIM / 64; ++kt) {
        const int kbase = kt << 6;

        // ---- V transpose: U.vs (fp32 [k][d]) -> Vt (bf16 [d][k]) ----
        {
            const int c = t & 63, k0 = (t >> 6) << 4;
            unsigned short vtmp[16];
#pragma unroll
            for (int e = 0; e < 16; ++e)
                vtmp[e] = (unsigned short)bf16rne(U.vs[(k0 + e) * 68 + c]);
            uint4 w0, w1;
            w0.x = vtmp[0]  | ((unsigned)vtmp[1]  << 16);
            w0.y = vtmp[2]  | ((unsigned)vtmp[3]  << 16);
            w0.z = vtmp[4]  | ((unsigned)vtmp[5]  << 16);
            w0.w = vtmp[6]  | ((unsigned)vtmp[7]  << 16);
            w1.x = vtmp[8]  | ((unsigned)vtmp[9]  << 16);
            w1.y = vtmp[10] | ((unsigned)vtmp[11] << 16);
            w1.z = vtmp[12] | ((unsigned)vtmp[13] << 16);
            w1.w = vtmp[14] | ((unsigned)vtmp[15] << 16);
            *(uint4*)&Vt[c * 72 + k0]     = w0;
            *(uint4*)&Vt[c * 72 + k0 + 8] = w1;
        }

        // ---- QK^T: 3-pass split-bf16 ----
        f32x4 sc[2][4];
#pragma unroll
        for (int i = 0; i < 2; ++i)
#pragma unroll
            for (int j = 0; j < 4; ++j) sc[i][j] = (f32x4){0.f, 0.f, 0.f, 0.f};
#pragma unroll
        for (int kk = 0; kk < 2; ++kk) {
            short8 bh8[4], bl8[4];
#pragma unroll
            for (int j = 0; j < 4; ++j) {
                bh8[j] = *(const short8*)&Kh[(j * 16 + lr) * 72 + kk * 32 + lg * 8];
                bl8[j] = *(const short8*)&Kl[(j * 16 + lr) * 72 + kk * 32 + lg * 8];
            }
#pragma unroll
            for (int i = 0; i < 2; ++i)
#pragma unroll
                for (int j = 0; j < 4; ++j) {
                    sc[i][j] = __builtin_amdgcn_mfma_f32_16x16x32_bf16(
                        qh[i][kk], bh8[j], sc[i][j], 0, 0, 0);
                    sc[i][j] = __builtin_amdgcn_mfma_f32_16x16x32_bf16(
                        qh[i][kk], bl8[j], sc[i][j], 0, 0, 0);
                    sc[i][j] = __builtin_amdgcn_mfma_f32_16x16x32_bf16(
                        ql[i][kk], bh8[j], sc[i][j], 0, 0, 0);
                }
        }

        // ---- mask + online softmax (rows: i*16+lg*4+rr, cols: j*16+lr) ----
        unsigned short pmv[2][4][4];
#pragma unroll
        for (int i = 0; i < 2; ++i) {
#pragma unroll
            for (int rr = 0; rr < 4; ++rr) {
                const int qrow = qb0 + w * 32 + i * 16 + lg * 4 + rr;
                const int*   mrow = mask + ((size_t)b * SDIM + qrow) * SDIM + kbase;
                const float* grow = gp   + ((size_t)b * SDIM + qrow) * SDIM + kbase;
                float sv[4];
#pragma unroll
                for (int j = 0; j < 4; ++j) {
                    int kc = j * 16 + lr;
                    bool ok = (mrow[kc] != 0) || (qrow == kbase + kc);
                    sv[j] = ok ? sc[i][j][rr] * 0.125f : -1.0e9f;
                }
                float tm = fmaxf(fmaxf(sv[0], sv[1]), fmaxf(sv[2], sv[3]));
#pragma unroll
                for (int off = 1; off < 16; off <<= 1)
                    tm = fmaxf(tm, __shfl_xor(tm, off));
                const int r = i * 4 + rr;
                float mn  = fmaxf(mreg[r], tm);
                float fac = __expf(mreg[r] - mn);  // first tile: 0
                float ts = 0.f, pj[4];
#pragma unroll
                for (int j = 0; j < 4; ++j) { pj[j] = __expf(sv[j] - mn); ts += pj[j]; }
#pragma unroll
                for (int off = 1; off < 16; off <<= 1)
                    ts += __shfl_xor(ts, off);
                lreg[r] = lreg[r] * fac + ts;      // gp NOT in denominator
                mreg[r] = mn;
#pragma unroll
                for (int j = 0; j < 4; ++j) pv[i][j][rr] *= fac;
#pragma unroll
                for (int j = 0; j < 4; ++j)
                    pmv[i][rr][j] =
                        (unsigned short)bf16rne(pj[j] * grow[j * 16 + lr]);
            }
        }

        __syncthreads();                           // b2: Vt ready; vs reads done

        if (kt < SDIM / 64 - 1) LOADKV(kbase + 64) // prefetch under PV

        // ---- write P*gp (own wave's rows only; lgkmcnt orders w/ reads) ----
#pragma unroll
        for (int i = 0; i < 2; ++i)
#pragma unroll
            for (int rr = 0; rr < 4; ++rr) {
                int row = w * 32 + i * 16 + lg * 4 + rr;
#pragma unroll
                for (int j = 0; j < 4; ++j)
                    U.pm[row * 72 + j * 16 + lr] = pmv[i][rr][j];
            }

        // ---- PV: single-pass bf16 ----
#pragma unroll
        for (int kk = 0; kk < 2; ++kk) {
            short8 pa[2], vb[4];
#pragma unroll
            for (int i = 0; i < 2; ++i)
                pa[i] = *(const short8*)&U.pm[(w * 32 + i * 16 + lr) * 72
                                              + kk * 32 + lg * 8];
#pragma unroll
            for (int j = 0; j < 4; ++j)
                vb[j] = *(const short8*)&Vt[(j * 16 + lr) * 72 + kk * 32 + lg * 8];
#pragma unroll
            for (int i = 0; i < 2; ++i)
#pragma unroll
                for (int j = 0; j < 4; ++j)
                    pv[i][j] = __builtin_amdgcn_mfma_f32_16x16x32_bf16(
                        pa[i], vb[j], pv[i][j], 0, 0, 0);
        }

        __syncthreads();                           // b3: PV reads done

        if (kt < SDIM / 64 - 1) {
            STOREKV()
            __syncthreads();                       // b1: next tile staged
        }
    }
#undef LOADKV
#undef STOREKV

    // ---- epilogue: out = pv / l ----
#pragma unroll
    for (int i = 0; i < 2; ++i)
#pragma unroll
        for (int rr = 0; rr < 4; ++rr) {
            int qrow  = qb0 + w * 32 + i * 16 + lg * 4 + rr;
            float inv = 1.f / lreg[i * 4 + rr];
            float* orow = Xo + ((size_t)b * SDIM + qrow) * DDIM + h * DKDIM;
#pragma unroll
            for (int j = 0; j < 4; ++j)
                orow[j * 16 + lr] = pv[i][j][rr] * inv;
        }
}

// ---------------------------------------------------------------------------
extern "C" void kernel_launch(void* const* d_in, const int* in_sizes, int n_in,
                              void* d_out, int out_size, void* d_ws, size_t ws_size,
                              hipStream_t stream)
{
    (void)in_sizes; (void)n_in; (void)out_size; (void)ws_size;
    const float* query = (const float*)d_in[0];
    const float* key_  = (const float*)d_in[1];
    const float* value = (const float*)d_in[2];
    const float* gp    = (const float*)d_in[3];
    const int*   mask  = (const int*)d_in[4];
    const float* Wq = (const float*)d_in[5];  const float* bq = (const float*)d_in[6];
    const float* Wk = (const float*)d_in[7];  const float* bk = (const float*)d_in[8];
    const float* Wv = (const float*)d_in[9];  const float* bv = (const float*)d_in[10];
    const float* Wo = (const float*)d_in[11]; const float* bo = (const float*)d_in[12];
    float* out = (float*)d_out;

    const size_t NE = (size_t)NBATCH * SDIM * DDIM;   // 8.39M floats each
    float* Qw = (float*)d_ws;          // [B,H,S,DK]
    float* Kw = Qw + NE;
    float* Vw = Kw + NE;
    float* Xo = Vw + NE;               // [B,S,D]  (ws total: 134 MB)

    dim3 blk(256);
    dim3 gproj(512);                                  // 128x128 tiles, swizzled
    hipLaunchKernelGGL(proj_mfma, gproj, blk, 0, stream, query, Wq, bq, Qw, 1);
    hipLaunchKernelGGL(proj_mfma, gproj, blk, 0, stream, key_,  Wk, bk, Kw, 1);
    hipLaunchKernelGGL(proj_mfma, gproj, blk, 0, stream, value, Wv, bv, Vw, 1);
    dim3 gattn(NBATCH * NHEAD * (SDIM / 128));        // 1024, XCD-swizzled
    hipLaunchKernelGGL(attn_mfma, gattn, blk, 0, stream, Qw, Kw, Vw, gp, mask, Xo);
    hipLaunchKernelGGL(proj_mfma, gproj, blk, 0, stream, Xo, Wo, bo, out, 0);
}